// Round 1
// baseline (612.844 us; speedup 1.0000x reference)
//
#include <hip/hip_runtime.h>
#include <hip/hip_bf16.h>

#define ALPHA 0.2f
constexpr int N_ROWS = 200000;
constexpr int IN_F   = 256;
constexpr int OUT_F  = 128;
constexpr int TM     = 32;                  // rows per chunk
constexpr int NCHUNK = N_ROWS / TM;         // 6250
constexpr int GRID   = 1024;

typedef __attribute__((ext_vector_type(4))) float f32x4;
typedef __attribute__((ext_vector_type(8))) short short8;

__device__ __forceinline__ unsigned short f2bf(float x) {
    __hip_bfloat16 h = __float2bfloat16(x);
    return __builtin_bit_cast(unsigned short, h);
}

__global__ __launch_bounds__(256) void fused_schema_attn(
    const float* __restrict__ tin, const float* __restrict__ o1,
    const float* __restrict__ o2,  const float* __restrict__ W,
    const float* __restrict__ s,   float* __restrict__ out)
{
    __shared__ float u_lds[IN_F];
    __shared__ float v_lds[IN_F];
    __shared__ __align__(16) unsigned short m_lds[TM][IN_F];  // bf16 bits, XOR-swizzled

    const int tid  = threadIdx.x;
    const int lane = tid & 63;
    const int wv   = tid >> 6;    // wave 0..3

    // ---- setup: u = W @ s_top, v = W @ s_bot (thread i owns W row i) ----
    {
        const float* wr = W + tid * OUT_F;
        float su = 0.f, sv = 0.f;
        #pragma unroll 8
        for (int f = 0; f < OUT_F; ++f) {
            float w = wr[f];
            su = fmaf(w, s[f], su);
            sv = fmaf(w, s[OUT_F + f], sv);
        }
        u_lds[tid] = su;
        v_lds[tid] = sv;
    }

    // ---- setup: B fragments in registers. wave wv owns cols [32wv, 32wv+32) ----
    // mfma_f32_16x16x32_bf16 B layout: lane holds B[k=(lane>>4)*8+j][col=lane&15]
    short8 Bfrag[2][8];
    {
        const int kb = (lane >> 4) << 3;
        #pragma unroll
        for (int ct = 0; ct < 2; ++ct) {
            const int col = (wv << 5) + (ct << 4) + (lane & 15);
            #pragma unroll
            for (int kt = 0; kt < 8; ++kt) {
                short8 b;
                #pragma unroll
                for (int j = 0; j < 8; ++j)
                    b[j] = (short)f2bf(W[(kt * 32 + kb + j) * OUT_F + col]);
                Bfrag[ct][kt] = b;
            }
        }
    }
    __syncthreads();

    // per-lane u,v slice: lane covers columns 4*lane .. 4*lane+3
    float u4[4], v4[4];
    #pragma unroll
    for (int j = 0; j < 4; ++j) {
        u4[j] = u_lds[(lane << 2) + j];
        v4[j] = v_lds[(lane << 2) + j];
    }

    for (int chunk = blockIdx.x; chunk < NCHUNK; chunk += GRID) {
        const int base = chunk * TM;

        // ---- phase 1: scores + softmax + mix -> m_lds (bf16) ----
        for (int i = 0; i < 8; ++i) {
            const int rloc = (i << 2) + wv;                    // this wave's row
            const int off  = (base + rloc) * IN_F + (lane << 2);
            f32x4 t4 = *reinterpret_cast<const f32x4*>(tin + off);
            f32x4 x1 = *reinterpret_cast<const f32x4*>(o1  + off);
            f32x4 x2 = *reinterpret_cast<const f32x4*>(o2  + off);

            float pa = 0.f, p0 = 0.f, p1 = 0.f, p2 = 0.f;
            #pragma unroll
            for (int j = 0; j < 4; ++j) {
                pa = fmaf(t4[j], u4[j], pa);
                p0 = fmaf(t4[j], v4[j], p0);
                p1 = fmaf(x1[j], v4[j], p1);
                p2 = fmaf(x2[j], v4[j], p2);
            }
            #pragma unroll
            for (int d = 32; d > 0; d >>= 1) {
                pa += __shfl_xor(pa, d);
                p0 += __shfl_xor(p0, d);
                p1 += __shfl_xor(p1, d);
                p2 += __shfl_xor(p2, d);
            }
            float e0 = pa + p0, e1 = pa + p1, e2 = pa + p2;
            e0 = e0 > 0.f ? e0 : ALPHA * e0;
            e1 = e1 > 0.f ? e1 : ALPHA * e1;
            e2 = e2 > 0.f ? e2 : ALPHA * e2;
            float mx = fmaxf(e0, fmaxf(e1, e2));
            float w0 = __expf(e0 - mx), w1 = __expf(e1 - mx), w2 = __expf(e2 - mx);
            float inv = 1.f / (w0 + w1 + w2);
            float a0 = w0 * inv, a1 = w1 * inv, a2 = w2 * inv;

            ushort4 mm;
            #pragma unroll
            for (int j = 0; j < 4; ++j) {
                float mval = a0 * t4[j] + a1 * x1[j] + a2 * x2[j];
                reinterpret_cast<unsigned short*>(&mm)[j] = f2bf(mval);
            }
            // swizzled write: logical byte 8*lane in row rloc, XOR bits 4..6 with row
            const int boff = (lane << 3) ^ ((rloc & 7) << 4);
            *reinterpret_cast<ushort4*>(
                reinterpret_cast<char*>(&m_lds[rloc][0]) + boff) = mm;
        }
        __syncthreads();

        // ---- phase 2: out_chunk = m @ W via MFMA ----
        f32x4 acc[2][2];
        #pragma unroll
        for (int rt = 0; rt < 2; ++rt)
            #pragma unroll
            for (int ct = 0; ct < 2; ++ct)
                acc[rt][ct] = f32x4{0.f, 0.f, 0.f, 0.f};

        const int kq = lane >> 4;   // 0..3
        #pragma unroll
        for (int rt = 0; rt < 2; ++rt) {
            const int row = (rt << 4) + (lane & 15);           // A row within chunk
            const char* rowp = reinterpret_cast<const char*>(&m_lds[row][0]);
            const int sw = (row & 7) << 4;
            #pragma unroll
            for (int kt = 0; kt < 8; ++kt) {
                // A layout: lane holds m[row][kt*32 + kq*8 + j], j=0..7 -> 16B
                const int aoff = ((kt << 6) + (kq << 4)) ^ sw;
                short8 a = *reinterpret_cast<const short8*>(rowp + aoff);
                acc[rt][0] = __builtin_amdgcn_mfma_f32_16x16x32_bf16(
                                 a, Bfrag[0][kt], acc[rt][0], 0, 0, 0);
                acc[rt][1] = __builtin_amdgcn_mfma_f32_16x16x32_bf16(
                                 a, Bfrag[1][kt], acc[rt][1], 0, 0, 0);
            }
        }

        // ---- store: D layout col=lane&15, row=(lane>>4)*4+j ----
        #pragma unroll
        for (int rt = 0; rt < 2; ++rt) {
            #pragma unroll
            for (int ct = 0; ct < 2; ++ct) {
                const int col = (wv << 5) + (ct << 4) + (lane & 15);
                #pragma unroll
                for (int j = 0; j < 4; ++j) {
                    const int row = base + (rt << 4) + (kq << 2) + j;
                    out[row * OUT_F + col] = acc[rt][ct][j];
                }
            }
        }
        __syncthreads();   // protect m_lds before next chunk overwrites it
    }
}

extern "C" void kernel_launch(void* const* d_in, const int* in_sizes, int n_in,
                              void* d_out, int out_size, void* d_ws, size_t ws_size,
                              hipStream_t stream) {
    (void)in_sizes; (void)n_in; (void)out_size; (void)d_ws; (void)ws_size;
    const float* tin = (const float*)d_in[0];
    const float* o1  = (const float*)d_in[1];
    const float* o2  = (const float*)d_in[2];
    const float* W   = (const float*)d_in[3];
    const float* s   = (const float*)d_in[4];
    float* out = (float*)d_out;
    fused_schema_attn<<<dim3(GRID), dim3(256), 0, stream>>>(tin, o1, o2, W, s, out);
}